// Round 6
// baseline (2291.365 us; speedup 1.0000x reference)
//
#include <hip/hip_runtime.h>

#define Bn 32
#define Tn 512
#define Cn 8
#define Hn 256
#define Gn 1024            // 4*Hn
#define NTHR 512           // 8 waves: 0-3 layer-1 crew, 4-7 layer-2 crew
#define SLC  16            // slices per channel (each WG owns 16 h-indices, 64 gate rows)
#define NBLK (Cn*2*SLC)    // 256 workgroups: (channel, batch-half, slice) -> 1 per CU
#define K2n  (Hn/2)        // 128 k-pairs
#define BUFS 4             // exchange buffers; coprime with tag period 3 -> exact freshness
#define EXU  (BUFS*Cn*K2n*Bn) // 8-byte units per layer exchange array
#define SLC4 (SLC*4)       // out-partial slots per (t,c): slice x wave

typedef __attribute__((ext_vector_type(8))) __bf16 bf16x8;
typedef __attribute__((ext_vector_type(8))) short  short8;
typedef __attribute__((ext_vector_type(4))) float  f32x4;
typedef __attribute__((ext_vector_type(4))) unsigned uintx4;
typedef unsigned long long u64;

__device__ __forceinline__ unsigned bfr(float f) {            // fp32 -> bf16 bits, RNE
    unsigned u = __float_as_uint(f);
    return (u + 0x7fffu + ((u >> 16) & 1u)) >> 16;
}
__device__ __forceinline__ float sigmf(float v)  { return 1.0f / (1.0f + __expf(-v)); }
__device__ __forceinline__ float tanh_f(float v) { return 1.0f - 2.0f / (__expf(2.0f * v) + 1.0f); }

__device__ __forceinline__ f32x4 mf(short8 a, short8 b, f32x4 c) {
    return __builtin_amdgcn_mfma_f32_16x16x32_bf16(
        __builtin_bit_cast(bf16x8, a), __builtin_bit_cast(bf16x8, b), c, 0, 0, 0);
}

// split 8 consecutive fp32 into bf16 hi + bf16 lo fragments
__device__ __forceinline__ void splitw(const float* __restrict__ p, short8& hi, short8& lo) {
    short8 h, l;
#pragma unroll
    for (int j = 0; j < 8; ++j) {
        const float v = p[j];
        const unsigned hb = bfr(v);
        h[j] = (short)hb;
        l[j] = (short)bfr(v - __uint_as_float(hb << 16));
    }
    hi = h; lo = l;
}

// agent-scope (Infinity-Cache) single-copy-atomic 8-byte ops (proven rounds 2/3/5)
__device__ __forceinline__ void ast64(u64* p, u64 v) {
    __hip_atomic_store(p, v, __ATOMIC_RELAXED, __HIP_MEMORY_SCOPE_AGENT);
}
__device__ __forceinline__ u64 ald64(const u64* p) {
    return __hip_atomic_load(p, __ATOMIC_RELAXED, __HIP_MEMORY_SCOPE_AGENT);
}
// workgroup-scope LDS atomics (plain ds ops, compiler-ordered, no caching)
__device__ __forceinline__ void astw(unsigned* p, unsigned v) {
    __hip_atomic_store(p, v, __ATOMIC_RELAXED, __HIP_MEMORY_SCOPE_WORKGROUP);
}
__device__ __forceinline__ unsigned aldw(const unsigned* p) {
    return __hip_atomic_load(p, __ATOMIC_RELAXED, __HIP_MEMORY_SCOPE_WORKGROUP);
}

__global__ void __launch_bounds__(NTHR, 2)
lstm_mfma(const float* __restrict__ x,
          const float* __restrict__ Wih1, const float* __restrict__ Whh1,
          const float* __restrict__ bih1, const float* __restrict__ bhh1,
          const float* __restrict__ Wih2, const float* __restrict__ Whh2,
          const float* __restrict__ bih2, const float* __restrict__ bhh2,
          const float* __restrict__ Wlin, const float* __restrict__ blin,
          float* __restrict__ out, void* __restrict__ wsv, int use_part) {
    // Wih2 fragments (off-critical-path matrix) parked in LDS by the L1 crew
    __shared__ short8  w2lds[4][8][2][64];     // [l1 wave][kk][hi/lo][lane] = 64 KiB
    __shared__ float   tbuf[8][16][20];        // per-wave 16x16 gate transpose (pad 20)
    __shared__ unsigned xp2b[4][4][16][16];    // [pair][buf][batch n][row] fp32|2-bit tag
    __shared__ unsigned prog[4];               // L2 progress per pair (xp2 WAR gate)

    // exchange: [4 buf][C][K2=128][B=32] u64 = (hi-pair dword, lo-pair dword);
    // lo-pair LSBs carry tag (t mod 3)+1, 0 = unwritten. BUFS=4 x period-3 tags:
    // a match implies EXACT step (stale = 12 steps old; skew <= 2 by induction).
    u64* EX1 = (u64*)wsv;
    u64* EX2 = EX1 + EXU;
    float* part = (float*)(EX2 + EXU);         // [T][C][SLC4][B] out partials

    const int tid  = threadIdx.x;
    const int wg   = blockIdx.x;
    const int c    = wg & 7;                   // channel
    const int s    = (wg >> 3) & 15;           // slice: h-indices s*16 .. s*16+15
    const int bh   = (wg >> 7) & 1;            // batch-half
    const int lane = tid & 63;
    const int wid  = tid >> 6;                 // 8 waves
    const int role = wid >> 2;                 // 0 = layer-1 crew, 1 = layer-2 crew
    const int w    = wid & 3;                  // wave-within-crew: h-indices w*4..w*4+3
    const int n    = lane & 15;                // batch col (B-frag) == cell batch
    const int q    = lane >> 4;                // quad
    const int bn   = bh * 16 + n;              // global batch

    // zero xp2 tags + progress counters (tag 0 = unwritten)
    for (int i = tid; i < 4 * 4 * 16 * 16; i += NTHR) ((unsigned*)xp2b)[i] = 0u;
    if (tid < 4) prog[tid] = 0u;

    // A-row packing: row idx rr in 0..15 <-> (type = rr>>2, m = rr&3);
    // global gate row g = type*256 + s*16 + w*4 + m. Lane n holds A-row n.
    const int grow = ((n >> 2) << 8) + s * 16 + w * 4 + (n & 3);
    const size_t wbase = (size_t)c * Gn * Hn + (size_t)grow * Hn + q * 8;

    if (role == 0) {
        // ================= LAYER-1 crew: Whh1 (regs) + Wih2 (LDS) =================
        short8 w1h[8], w1l[8];
#pragma unroll
        for (int kk = 0; kk < 8; ++kk) {
            splitw(Whh1 + wbase + kk * 32, w1h[kk], w1l[kk]);
            short8 th, tl;
            splitw(Wih2 + wbase + kk * 32, th, tl);
            w2lds[w][kk][0][lane] = th;
            w2lds[w][kk][1][lane] = tl;
        }
        // per-lane cell constants: this lane's cell is (j = w*4+q, b = n)
        float wi1c[4], bs1c[4];
#pragma unroll
        for (int tt = 0; tt < 4; ++tt) {
            const int g = tt * 256 + s * 16 + w * 4 + q;
            wi1c[tt] = Wih1[c * Gn + g];
            bs1c[tt] = bih1[c * Gn + g] + bhh1[c * Gn + g];
        }
        float* tb = &tbuf[wid][0][0];
        __syncthreads();                       // xp2b zero + w2lds visible

        float c1 = 0.0f;
        for (int t = 0; t <= Tn; ++t) {        // t == Tn: xp2[Tn-1] only
            const bool doCell = (t < Tn);
            unsigned pg = aldw(&prog[w]);      // early gate fetch, checked late
            const float xv = doCell ? x[((size_t)bn * Tn + t) * Cn + c] : 0.0f;

            // ---- poll E1 for h1[t-1] (the L1 critical wait) ----
            const u64* E1r = EX1 + (size_t)(((t + 3) & 3) * Cn + c) * K2n * Bn;
            const unsigned ptag = (unsigned)((t + 2) % 3) + 1u;
            const unsigned em = (ptag & 1u) | ((ptag & 2u) << 15);
            const bool chk = (t >= 1);
            short8 f1h[8], f1l[8];
            for (;;) {
                unsigned bad = 0;
#pragma unroll
                for (int kk = 0; kk < 8; ++kk) {
                    uintx4 ah, al;
#pragma unroll
                    for (int j2 = 0; j2 < 4; ++j2) {
                        const int k2 = kk * 16 + q * 4 + j2;
                        const u64 v = ald64(E1r + k2 * Bn + bn);
                        ah[j2] = (unsigned)v;
                        al[j2] = (unsigned)(v >> 32);
                        bad |= (al[j2] ^ em) & 0x00010001u;
                    }
                    f1h[kk] = __builtin_bit_cast(short8, ah);
                    f1l[kk] = __builtin_bit_cast(short8, al);
                }
                if (!chk || __all((int)(bad == 0))) break;
                __builtin_amdgcn_s_sleep(1);
            }

            if (doCell) {
                // ---- Whh1, full K per wave: 24 MFMAs, no cross-wave reduction ----
                f32x4 aa = {0,0,0,0}, ax = {0,0,0,0};
#pragma unroll
                for (int kk = 0; kk < 8; ++kk) {
                    aa = mf(w1h[kk], f1h[kk], aa);
                    ax = mf(w1l[kk], f1h[kk], mf(w1h[kk], f1l[kk], ax));
                }
                // in-wave 4x4 quad transpose via private LDS (no barrier)
#pragma unroll
                for (int r = 0; r < 4; ++r) tb[n * 20 + q * 4 + r] = aa[r] + ax[r];
                asm volatile("s_waitcnt lgkmcnt(0)" ::: "memory");
                float gv[4];
#pragma unroll
                for (int tt = 0; tt < 4; ++tt) gv[tt] = tb[n * 20 + tt * 4 + q];

                // ---- cell1: lane owns (j = w*4+q, b = n) ----
                const float iv = sigmf (gv[0] + xv * wi1c[0] + bs1c[0]);
                const float fv = sigmf (gv[1] + xv * wi1c[1] + bs1c[1]);
                const float gg = tanh_f(gv[2] + xv * wi1c[2] + bs1c[2]);
                const float ov = sigmf (gv[3] + xv * wi1c[3] + bs1c[3]);
                c1 = fv * c1 + iv * gg;
                const float h1v = ov * tanh_f(c1);

                // ---- publish h1[t]: pair (j even, j+1) via lane^16 ----
                const unsigned hb = bfr(h1v);
                const unsigned lb = bfr(h1v - __uint_as_float(hb << 16));
                const unsigned packed = (hb << 16) | lb;
                const unsigned nbp = (unsigned)__shfl_xor((int)packed, 16, 64);
                const unsigned ctag = (unsigned)(t % 3) + 1u;
                const unsigned cm = (ctag & 1u) | ((ctag & 2u) << 15);
                if ((q & 1) == 0) {
                    const unsigned hip = (packed >> 16) | (nbp & 0xffff0000u);
                    unsigned lop = (packed & 0xffffu) | (nbp << 16);
                    lop = (lop & 0xFFFEFFFEu) | cm;
                    const int k2p = s * 8 + w * 2 + (q >> 1);
                    ast64(EX1 + (size_t)((t & 3) * Cn + c) * K2n * Bn + k2p * Bn + bn,
                          (u64)hip | ((u64)lop << 32));
                }
            }

            // ---- off-chain: xp2[t-1] = Wih2 . h1[t-1] -> LDS to partner L2 wave ----
            if (t >= 1) {
                f32x4 aa2 = {0,0,0,0}, ax2 = {0,0,0,0};
#pragma unroll
                for (int kk = 0; kk < 8; ++kk) {
                    const short8 wh = w2lds[w][kk][0][lane];
                    const short8 wl8 = w2lds[w][kk][1][lane];
                    aa2 = mf(wh, f1h[kk], aa2);
                    ax2 = mf(wl8, f1h[kk], mf(wh, f1l[kk], ax2));
                }
                // WAR gate: overwriting xp2[t-5]; partner must be past it
                while ((int)pg < t - 4) {
                    __builtin_amdgcn_s_sleep(2);
                    pg = aldw(&prog[w]);
                }
                const unsigned utag = (unsigned)((t - 1) % 3) + 1u;
                unsigned* dst = &xp2b[w][(t - 1) & 3][n][q * 4];
#pragma unroll
                for (int r = 0; r < 4; ++r) {
                    const unsigned b = __float_as_uint(aa2[r] + ax2[r]);
                    astw(dst + r, (b & ~3u) | utag);   // 2-LSB tag (<= 3 ulp noise)
                }
            }
        }
    } else {
        // ================= LAYER-2 crew: Whh2 (regs) + xp2 from LDS =================
        short8 w3h[8], w3l[8];
#pragma unroll
        for (int kk = 0; kk < 8; ++kk)
            splitw(Whh2 + wbase + kk * 32, w3h[kk], w3l[kk]);
        float bs2c[4];
#pragma unroll
        for (int tt = 0; tt < 4; ++tt) {
            const int g = tt * 256 + s * 16 + w * 4 + q;
            bs2c[tt] = bih2[c * Gn + g] + bhh2[c * Gn + g];
        }
        const float wl = Wlin[c * Hn + s * 16 + w * 4 + q];
        const float bl = blin[c];
        float* tb = &tbuf[wid][0][0];
        __syncthreads();

        float c2 = 0.0f;
        for (int u = 0; u < Tn; ++u) {
            // ---- poll E2 for h2[u-1] (the L2 critical wait) ----
            const u64* E2r = EX2 + (size_t)(((u + 3) & 3) * Cn + c) * K2n * Bn;
            const unsigned ptag = (unsigned)((u + 2) % 3) + 1u;
            const unsigned em = (ptag & 1u) | ((ptag & 2u) << 15);
            const bool chk = (u >= 1);
            short8 f2h[8], f2l[8];
            for (;;) {
                unsigned bad = 0;
#pragma unroll
                for (int kk = 0; kk < 8; ++kk) {
                    uintx4 ah, al;
#pragma unroll
                    for (int j2 = 0; j2 < 4; ++j2) {
                        const int k2 = kk * 16 + q * 4 + j2;
                        const u64 v = ald64(E2r + k2 * Bn + bn);
                        ah[j2] = (unsigned)v;
                        al[j2] = (unsigned)(v >> 32);
                        bad |= (al[j2] ^ em) & 0x00010001u;
                    }
                    f2h[kk] = __builtin_bit_cast(short8, ah);
                    f2l[kk] = __builtin_bit_cast(short8, al);
                }
                if (!chk || __all((int)(bad == 0))) break;
                __builtin_amdgcn_s_sleep(1);
            }

            // ---- Whh2: 24 MFMAs ----
            f32x4 aa = {0,0,0,0}, ax = {0,0,0,0};
#pragma unroll
            for (int kk = 0; kk < 8; ++kk) {
                aa = mf(w3h[kk], f2h[kk], aa);
                ax = mf(w3l[kk], f2h[kk], mf(w3h[kk], f2l[kk], ax));
            }
#pragma unroll
            for (int r = 0; r < 4; ++r) tb[n * 20 + q * 4 + r] = aa[r] + ax[r];
            asm volatile("s_waitcnt lgkmcnt(0)" ::: "memory");
            float gv[4];
#pragma unroll
            for (int tt = 0; tt < 4; ++tt) gv[tt] = tb[n * 20 + tt * 4 + q];

            // ---- xp2[u] from partner L1 wave (tag-validated; usually instant) ----
            const unsigned etag = (unsigned)(u % 3) + 1u;
            const unsigned* src = &xp2b[w][u & 3][n][0];
            unsigned bw0, bw1, bw2, bw3;
            for (;;) {
                bw0 = aldw(src + 0 * 4 + q);
                bw1 = aldw(src + 1 * 4 + q);
                bw2 = aldw(src + 2 * 4 + q);
                bw3 = aldw(src + 3 * 4 + q);
                const unsigned bad = ((bw0 & 3u) ^ etag) | ((bw1 & 3u) ^ etag) |
                                     ((bw2 & 3u) ^ etag) | ((bw3 & 3u) ^ etag);
                if (__all((int)(bad == 0))) break;
                __builtin_amdgcn_s_sleep(1);
            }
            astw(&prog[w], (unsigned)(u + 1));   // unblock partner's xp2 WAR

            // ---- cell2 ----
            const float iv = sigmf (gv[0] + __uint_as_float(bw0) + bs2c[0]);
            const float fv = sigmf (gv[1] + __uint_as_float(bw1) + bs2c[1]);
            const float gg = tanh_f(gv[2] + __uint_as_float(bw2) + bs2c[2]);
            const float ov = sigmf (gv[3] + __uint_as_float(bw3) + bs2c[3]);
            c2 = fv * c2 + iv * gg;
            const float h2v = ov * tanh_f(c2);

            // ---- publish h2[u] (last step has no reader) ----
            const unsigned hb = bfr(h2v);
            const unsigned lb = bfr(h2v - __uint_as_float(hb << 16));
            const unsigned packed = (hb << 16) | lb;
            const unsigned nbp = (unsigned)__shfl_xor((int)packed, 16, 64);
            if (u < Tn - 1 && (q & 1) == 0) {
                const unsigned cm = (etag & 1u) | ((etag & 2u) << 15);
                const unsigned hip = (packed >> 16) | (nbp & 0xffff0000u);
                unsigned lop = (packed & 0xffffu) | (nbp << 16);
                lop = (lop & 0xFFFEFFFEu) | cm;
                const int k2p = s * 8 + w * 2 + (q >> 1);
                ast64(EX2 + (size_t)((u & 3) * Cn + c) * K2n * Bn + k2p * Bn + bn,
                      (u64)hip | ((u64)lop << 32));
            }

            // ---- out partial: reduce this wave's 4 h over quads ----
            float pv = h2v * wl;
            pv += __shfl_xor(pv, 16, 64);
            pv += __shfl_xor(pv, 32, 64);
            if (q == 0) {
                if (use_part) {
                    part[(((size_t)u * Cn + c) * SLC4 + (s * 4 + w)) * Bn + bn] = pv;
                } else {
                    atomicAdd(&out[((size_t)bn * Tn + u) * Cn + c],
                              pv + ((s == 0 && w == 0) ? bl : 0.0f));
                }
            }
        }
    }
}

__global__ void reduce_out(const float* __restrict__ part, const float* __restrict__ blin,
                           float* __restrict__ out) {
    const int t = blockIdx.x;           // 512
    const int c = threadIdx.x >> 5;     // 8
    const int b = threadIdx.x & 31;     // 32
    float v = blin[c];
#pragma unroll
    for (int s4 = 0; s4 < SLC4; ++s4)
        v += part[(((size_t)t * Cn + c) * SLC4 + s4) * Bn + b];
    out[(b * Tn + t) * Cn + c] = v;
}

extern "C" void kernel_launch(void* const* d_in, const int* in_sizes, int n_in,
                              void* d_out, int out_size, void* d_ws, size_t ws_size,
                              hipStream_t stream) {
    const float* x    = (const float*)d_in[0];
    const float* Wih1 = (const float*)d_in[1];
    const float* Whh1 = (const float*)d_in[2];
    const float* bih1 = (const float*)d_in[3];
    const float* bhh1 = (const float*)d_in[4];
    const float* Wih2 = (const float*)d_in[5];
    const float* Whh2 = (const float*)d_in[6];
    const float* bih2 = (const float*)d_in[7];
    const float* bhh2 = (const float*)d_in[8];
    const float* Wlin = (const float*)d_in[9];
    const float* blin = (const float*)d_in[10];
    float* out = (float*)d_out;

    const size_t h_bytes    = (size_t)2 * EXU * sizeof(u64);                  // 2 MiB
    const size_t part_bytes = (size_t)Tn * Cn * SLC4 * Bn * sizeof(float);    // 32 MiB
    const int use_part = (ws_size >= h_bytes + part_bytes) ? 1 : 0;

    hipMemsetAsync(d_ws, 0, h_bytes, stream);   // zero h-exchange (tag 0 = unwritten)
    if (!use_part)
        hipMemsetAsync(d_out, 0, (size_t)out_size * sizeof(float), stream);

    lstm_mfma<<<NBLK, NTHR, 0, stream>>>(
        x, Wih1, Whh1, bih1, bhh1, Wih2, Whh2, bih2, bhh2, Wlin, blin, out, d_ws, use_part);

    if (use_part) {
        const float* part = (const float*)((const char*)d_ws + h_bytes);
        reduce_out<<<Tn, Cn * Bn, 0, stream>>>(part, blin, out);
    }
}

// Round 7
// 2114.244 us; speedup vs baseline: 1.0838x; 1.0838x over previous
//
#include <hip/hip_runtime.h>

#define Bn 32
#define Tn 512
#define Cn 8
#define Hn 256
#define Gn 1024            // 4*Hn
#define NTHR 256           // 4 waves: (kg = K-half, mh = M-half)
#define SLC  16            // slices per channel (each owns 16 h-indices, 64 gate rows)
#define NBLK (Cn*2*SLC)    // 256 workgroups: (channel, batch-half, slice) -> 1 per CU
#define K2n  (Hn/2)        // 128 k-pairs
#define BUFS 4             // exchange buffers; coprime with tag period 3 -> exact freshness
#define EXU  (BUFS*Cn*K2n*Bn) // 8-byte units per layer exchange array
#define GP2  18            // gate-buffer pitch: quad stride 72B = 8 banks -> 2-way (free)

typedef __attribute__((ext_vector_type(8))) __bf16 bf16x8;
typedef __attribute__((ext_vector_type(8))) short  short8;
typedef __attribute__((ext_vector_type(4))) float  f32x4;
typedef __attribute__((ext_vector_type(4))) unsigned uintx4;
typedef unsigned long long u64;

__device__ __forceinline__ unsigned bfr(float f) {            // fp32 -> bf16 bits, RNE
    unsigned u = __float_as_uint(f);
    return (u + 0x7fffu + ((u >> 16) & 1u)) >> 16;
}
__device__ __forceinline__ float sigmf(float v)  { return 1.0f / (1.0f + __expf(-v)); }
__device__ __forceinline__ float tanh_f(float v) { return 1.0f - 2.0f / (__expf(2.0f * v) + 1.0f); }

__device__ __forceinline__ f32x4 mf(short8 a, short8 b, f32x4 c) {
    return __builtin_amdgcn_mfma_f32_16x16x32_bf16(
        __builtin_bit_cast(bf16x8, a), __builtin_bit_cast(bf16x8, b), c, 0, 0, 0);
}

// split 8 consecutive fp32 into bf16 hi + bf16 lo fragments
__device__ __forceinline__ void splitw(const float* __restrict__ p, short8& hi, short8& lo) {
    short8 h, l;
#pragma unroll
    for (int j = 0; j < 8; ++j) {
        const float v = p[j];
        const unsigned hb = bfr(v);
        h[j] = (short)hb;
        l[j] = (short)bfr(v - __uint_as_float(hb << 16));
    }
    hi = h; lo = l;
}

// agent-scope (Infinity-Cache) single-copy-atomic 8-byte ops.
// Tag and data travel in ONE atomic word -> no ordering/fence/scope assumptions.
__device__ __forceinline__ void ast64(u64* p, u64 v) {
    __hip_atomic_store(p, v, __ATOMIC_RELAXED, __HIP_MEMORY_SCOPE_AGENT);
}
__device__ __forceinline__ u64 ald64(const u64* p) {
    return __hip_atomic_load(p, __ATOMIC_RELAXED, __HIP_MEMORY_SCOPE_AGENT);
}

__global__ void __launch_bounds__(NTHR, 1)
lstm_mfma(const float* __restrict__ x,
          const float* __restrict__ Wih1, const float* __restrict__ Whh1,
          const float* __restrict__ bih1, const float* __restrict__ bhh1,
          const float* __restrict__ Wih2, const float* __restrict__ Whh2,
          const float* __restrict__ bih2, const float* __restrict__ bhh2,
          const float* __restrict__ Wlin, const float* __restrict__ blin,
          float* __restrict__ out, void* __restrict__ wsv, int use_part) {
    __shared__ float g1buf[2 * 64 * GP2];   // [kg][64 gate rows][16 b] layer-1 K-partials
    __shared__ float g2buf[2 * 64 * GP2];   // layer-2 K-partials

    // exchange arrays: [4 buf][C][K2=128][B=32] of (hi-pair dword, lo-pair dword)
    // lo-pair LSBs (u64 bits 32,48) carry a 2-bit step tag = (t mod 3)+1; 0 = unwritten.
    // BUFS=4 with tag period 3 (coprime): a matching tag implies data from EXACTLY
    // the expected step (stale candidates are 12 steps old, excluded by the
    // validation induction: observing tag t-1 proves all peers are past step t-1).
    u64* EX1 = (u64*)wsv;
    u64* EX2 = EX1 + EXU;
    float* part = (float*)(EX2 + EXU);      // [T][C][SLC][B] out partials

    const int tid  = threadIdx.x;
    const int wg   = blockIdx.x;
    const int c    = wg & 7;               // channel
    const int s    = (wg >> 3) & 15;       // slice: h-indices s*16 .. s*16+15
    const int bh   = (wg >> 7) & 1;        // batch-half: independent pipeline
    const int lane = tid & 63;
    const int wid  = tid >> 6;             // 4 waves
    const int kg   = wid & 1;              // K-group: k in [kg*128, kg*128+128)
    const int mh   = wid >> 1;             // M-half: rows mh*32 .. mh*32+31
    const int n    = lane & 15;
    const int quad = lane >> 4;
    const int bn   = bh * 16 + n;          // global batch of this lane's B-column

    // ---- permanent A-fragments: 3 weight matrices, 2 M-tiles, bf16 hi+lo, in VGPRs ----
    short8 w1h[2][4], w1l[2][4], w2h[2][4], w2l[2][4], w3h[2][4], w3l[2][4];
#pragma unroll
    for (int mt = 0; mt < 2; ++mt) {
        const int r = mh * 32 + mt * 16 + n;                  // wg row (0..63)
        const size_t g = (size_t)((r >> 4) * Hn + s * 16 + (r & 15));
        const size_t base = (size_t)c * Gn * Hn + g * Hn + kg * 128 + quad * 8;
#pragma unroll
        for (int kk = 0; kk < 4; ++kk) {
            splitw(Whh1 + base + kk * 32, w1h[mt][kk], w1l[mt][kk]);
            splitw(Wih2 + base + kk * 32, w2h[mt][kk], w2l[mt][kk]);
            splitw(Whh2 + base + kk * 32, w3h[mt][kk], w3l[mt][kk]);
        }
    }

    // epilogue constants for the 8 accumulator rows (row = mh*32 + mt*16 + quad*4 + reg)
    float wi1_r[2][4], bs1_r[2][4], bs2_r[2][4];
#pragma unroll
    for (int mt = 0; mt < 2; ++mt)
#pragma unroll
        for (int reg = 0; reg < 4; ++reg) {
            const int r = mh * 32 + mt * 16 + quad * 4 + reg;
            const int g = (r >> 4) * Hn + s * 16 + (r & 15);
            wi1_r[mt][reg] = Wih1[c * Gn + g];
            bs1_r[mt][reg] = bih1[c * Gn + g] + bhh1[c * Gn + g];
            bs2_r[mt][reg] = bih2[c * Gn + g] + bhh2[c * Gn + g];
        }

    // cell-update mapping: thread -> (jj = tid&15 h-idx within slice, bb = tid>>4 batch)
    const int jj = tid & 15;
    const int bb = tid >> 4;               // 0..15
    const int gb = bh * 16 + bb;           // global batch
    const float wl = Wlin[c * Hn + s * 16 + jj];
    const float bl = blin[c];

    float c1 = 0.0f, c2 = 0.0f;

    for (int t = 0; t <= Tn; ++t) {
        const bool doA = (t < Tn);      // layer-1 step t
        const bool doB = (t >= 1);      // layer-2 step t-1 (pipelined one behind)
        const int wb = t & 3;           // write buffer
        const int rb = (t + 3) & 3;     // read buffer (t-1 mod 4)
        const unsigned ctag = (unsigned)(t % 3) + 1u;
        const unsigned ptag = (unsigned)((t + 2) % 3) + 1u;

        const float xv = doA ? x[(bn * Tn + t) * Cn + c] : 0.0f;

        const u64* E1 = EX1 + (size_t)(rb * Cn + c) * K2n * Bn;
        const u64* E2 = EX2 + (size_t)(rb * Cn + c) * K2n * Bn;
        const unsigned em = (ptag & 1u) | ((ptag & 2u) << 15);   // expected bits at lo0,lo16
        const bool chk1 = (t >= 1);     // E1 first written at producer step 0
        const bool chk2 = (t >= 2);     // E2 first written at producer step 1

        // ---- stage A: 1-word-per-lane probe. Cuts steady-state poll traffic ~16x
        // (64KB -> 4KB per WG-attempt), decongesting the IC so producer stores become
        // visible fast. k2 = kg*64+lane covers all 64 k-rows of this K-half (every
        // producer slice 8x). Purely heuristic: stage B below remains the correctness
        // gate, so probe coverage gaps can only cost a rare extra full pass.
        {
            const size_t poff = (size_t)(kg * 64 + lane) * Bn + bn;
            if (chk1 | chk2) {
                for (;;) {
                    unsigned bad = 0;
                    if (chk2) bad |= ((unsigned)(ald64(E2 + poff) >> 32) ^ em) & 0x00010001u;
                    if (chk1) bad |= ((unsigned)(ald64(E1 + poff) >> 32) ^ em) & 0x00010001u;
                    if (__all((int)(bad == 0))) break;
                    __builtin_amdgcn_s_sleep(1);
                }
            }
        }

        // ---- stage B: full tag-validated loads (normally exactly one pass) ----
        short8 f2h[4], f2l[4], f1h[4], f1l[4];
        bool got1 = false, got2 = false;
        for (;;) {
            unsigned bad1 = 0, bad2 = 0;
            if (!got2) {
#pragma unroll
                for (int kk = 0; kk < 4; ++kk) {
                    uintx4 a2h, a2l;
#pragma unroll
                    for (int j2 = 0; j2 < 4; ++j2) {
                        const int k2 = kg * 64 + kk * 16 + quad * 4 + j2;
                        const u64 v2 = ald64(E2 + k2 * Bn + bn);
                        a2h[j2] = (unsigned)v2;
                        a2l[j2] = (unsigned)(v2 >> 32);
                        bad2 |= (a2l[j2] ^ em) & 0x00010001u;
                    }
                    f2h[kk] = __builtin_bit_cast(short8, a2h);
                    f2l[kk] = __builtin_bit_cast(short8, a2l);
                }
            }
            if (!got1) {
#pragma unroll
                for (int kk = 0; kk < 4; ++kk) {
                    uintx4 a1h, a1l;
#pragma unroll
                    for (int j2 = 0; j2 < 4; ++j2) {
                        const int k2 = kg * 64 + kk * 16 + quad * 4 + j2;
                        const u64 v1 = ald64(E1 + k2 * Bn + bn);
                        a1h[j2] = (unsigned)v1;
                        a1l[j2] = (unsigned)(v1 >> 32);
                        bad1 |= (a1l[j2] ^ em) & 0x00010001u;
                    }
                    f1h[kk] = __builtin_bit_cast(short8, a1h);
                    f1l[kk] = __builtin_bit_cast(short8, a1l);
                }
            }
            if (!got2) got2 = !chk2 || __all((int)(bad2 == 0));
            if (!got1) got1 = !chk1 || __all((int)(bad1 == 0));
            if (got1 && got2) break;
            __builtin_amdgcn_s_sleep(1);   // throttle retry flood
        }

        f32x4 a1a[2] = {{0,0,0,0},{0,0,0,0}}, a1x[2] = {{0,0,0,0},{0,0,0,0}};
        f32x4 a2a[2] = {{0,0,0,0},{0,0,0,0}}, a2x[2] = {{0,0,0,0},{0,0,0,0}};
#pragma unroll
        for (int kk = 0; kk < 4; ++kk)
#pragma unroll
            for (int mt = 0; mt < 2; ++mt) {
                a2a[mt] = mf(w3h[mt][kk], f2h[kk], a2a[mt]);                       // Whh2.h2
                a2x[mt] = mf(w3l[mt][kk], f2h[kk], mf(w3h[mt][kk], f2l[kk], a2x[mt]));
                a1a[mt] = mf(w1h[mt][kk], f1h[kk], a1a[mt]);                       // Whh1.h1
                a1x[mt] = mf(w1l[mt][kk], f1h[kk], mf(w1h[mt][kk], f1l[kk], a1x[mt]));
                a2a[mt] = mf(w2h[mt][kk], f1h[kk], a2a[mt]);                       // Wih2.h1
                a2x[mt] = mf(w2l[mt][kk], f1h[kk], mf(w2h[mt][kk], f1l[kk], a2x[mt]));
            }

        // ---- write K-partial gates to LDS (C/D layout: col=lane&15, row=quad*4+reg) ----
#pragma unroll
        for (int mt = 0; mt < 2; ++mt)
#pragma unroll
            for (int reg = 0; reg < 4; ++reg) {
                const int r = mh * 32 + mt * 16 + quad * 4 + reg;      // 0..63
                const int off = (kg * 64 + r) * GP2 + n;
                float e1 = a1a[mt][reg] + a1x[mt][reg];
                float e2 = a2a[mt][reg] + a2x[mt][reg];
                if (kg == 0) {                       // bias/x terms added once
                    e1 += xv * wi1_r[mt][reg] + bs1_r[mt][reg];
                    e2 += bs2_r[mt][reg];
                }
                g1buf[off] = e1;
                g2buf[off] = e2;
            }
        __syncthreads();

        const unsigned cm = (ctag & 1u) | ((ctag & 2u) << 15);   // publish tag bits

        // ---- layer-1 cell update, publish h1[t] as tagged 8-byte atomic stores ----
        if (doA) {
            const float iv = sigmf (g1buf[jj * GP2 + bb]        + g1buf[(64 + jj) * GP2 + bb]);
            const float fv = sigmf (g1buf[(16 + jj) * GP2 + bb] + g1buf[(80 + jj) * GP2 + bb]);
            const float gv = tanh_f(g1buf[(32 + jj) * GP2 + bb] + g1buf[(96 + jj) * GP2 + bb]);
            const float ov = sigmf (g1buf[(48 + jj) * GP2 + bb] + g1buf[(112 + jj) * GP2 + bb]);
            c1 = fv * c1 + iv * gv;
            const float h1v = ov * tanh_f(c1);
            const unsigned hb = bfr(h1v);
            const unsigned lb = bfr(h1v - __uint_as_float(hb << 16));
            const unsigned packed = (hb << 16) | lb;
            const unsigned nbp = (unsigned)__shfl_xor((int)packed, 1, 64);
            if ((jj & 1) == 0) {
                const unsigned hip = (packed >> 16) | (nbp & 0xffff0000u);
                unsigned lop = (packed & 0xffffu) | (nbp << 16);
                lop = (lop & 0xFFFEFFFEu) | cm;                  // steal lo LSBs for tag
                const int k2 = s * 8 + (jj >> 1);
                ast64(EX1 + (size_t)(wb * Cn + c) * K2n * Bn + k2 * Bn + gb,
                      (u64)hip | ((u64)lop << 32));
            }
        }
        // ---- layer-2 cell update, publish h2[t-1], out partial ----
        if (doB) {
            const float iv = sigmf (g2buf[jj * GP2 + bb]        + g2buf[(64 + jj) * GP2 + bb]);
            const float fv = sigmf (g2buf[(16 + jj) * GP2 + bb] + g2buf[(80 + jj) * GP2 + bb]);
            const float gv = tanh_f(g2buf[(32 + jj) * GP2 + bb] + g2buf[(96 + jj) * GP2 + bb]);
            const float ov = sigmf (g2buf[(48 + jj) * GP2 + bb] + g2buf[(112 + jj) * GP2 + bb]);
            c2 = fv * c2 + iv * gv;
            const float h2v = ov * tanh_f(c2);
            if (t < Tn) {                 // last iteration's h2 has no reader
                const unsigned hb = bfr(h2v);
                const unsigned lb = bfr(h2v - __uint_as_float(hb << 16));
                const unsigned packed = (hb << 16) | lb;
                const unsigned nbp = (unsigned)__shfl_xor((int)packed, 1, 64);
                if ((jj & 1) == 0) {
                    const unsigned hip = (packed >> 16) | (nbp & 0xffff0000u);
                    unsigned lop = (packed & 0xffffu) | (nbp << 16);
                    lop = (lop & 0xFFFEFFFEu) | cm;
                    const int k2 = s * 8 + (jj >> 1);
                    ast64(EX2 + (size_t)(wb * Cn + c) * K2n * Bn + k2 * Bn + gb,
                          (u64)hip | ((u64)lop << 32));
                }
            } else {
                (void)__shfl_xor(0, 1, 64);          // keep shuffle pattern uniform
            }

            float pv = h2v * wl;                      // partial of out over this slice's 16 h
            pv += __shfl_xor(pv, 1, 64);
            pv += __shfl_xor(pv, 2, 64);
            pv += __shfl_xor(pv, 4, 64);
            pv += __shfl_xor(pv, 8, 64);
            if (jj == 0) {
                if (use_part) {
                    part[(((t - 1) * Cn + c) * SLC + s) * Bn + gb] = pv;
                } else {
                    atomicAdd(&out[(gb * Tn + (t - 1)) * Cn + c], pv + (s == 0 ? bl : 0.0f));
                }
            }
        }

        __syncthreads();   // WAR on gate LDS buffers (no global barrier needed)
    }
}

__global__ void reduce_out(const float* __restrict__ part, const float* __restrict__ blin,
                           float* __restrict__ out) {
    const int t = blockIdx.x;           // 512
    const int c = threadIdx.x >> 5;     // 8
    const int b = threadIdx.x & 31;     // 32
    float v = blin[c];
#pragma unroll
    for (int s = 0; s < SLC; ++s) v += part[((t * Cn + c) * SLC + s) * Bn + b];
    out[(b * Tn + t) * Cn + c] = v;
}

extern "C" void kernel_launch(void* const* d_in, const int* in_sizes, int n_in,
                              void* d_out, int out_size, void* d_ws, size_t ws_size,
                              hipStream_t stream) {
    const float* x    = (const float*)d_in[0];
    const float* Wih1 = (const float*)d_in[1];
    const float* Whh1 = (const float*)d_in[2];
    const float* bih1 = (const float*)d_in[3];
    const float* bhh1 = (const float*)d_in[4];
    const float* Wih2 = (const float*)d_in[5];
    const float* Whh2 = (const float*)d_in[6];
    const float* bih2 = (const float*)d_in[7];
    const float* bhh2 = (const float*)d_in[8];
    const float* Wlin = (const float*)d_in[9];
    const float* blin = (const float*)d_in[10];
    float* out = (float*)d_out;

    const size_t h_bytes    = (size_t)2 * EXU * sizeof(u64);                // 2 MiB
    const size_t part_bytes = (size_t)Tn * Cn * SLC * Bn * sizeof(float);   // 8 MiB
    const int use_part = (ws_size >= h_bytes + part_bytes) ? 1 : 0;

    hipMemsetAsync(d_ws, 0, h_bytes, stream);   // zero h-exchange (tag 0 = unwritten)
    if (!use_part)
        hipMemsetAsync(d_out, 0, (size_t)out_size * sizeof(float), stream);

    lstm_mfma<<<NBLK, NTHR, 0, stream>>>(
        x, Wih1, Whh1, bih1, bhh1, Wih2, Whh2, bih2, bhh2, Wlin, blin, out, d_ws, use_part);

    if (use_part) {
        const float* part = (const float*)((const char*)d_ws + h_bytes);
        reduce_out<<<Tn, Cn * Bn, 0, stream>>>(part, blin, out);
    }
}

// Round 8
// 1786.782 us; speedup vs baseline: 1.2824x; 1.1833x over previous
//
#include <hip/hip_runtime.h>

#define Bn 32
#define Tn 512
#define Cn 8
#define Hn 256
#define Gn 1024            // 4*Hn
#define NTHR 256           // 4 waves: (kg = K-half, mh = M-half)
#define SLC  16            // slices per channel (each owns 16 h-indices, 64 gate rows)
#define NBLK (Cn*2*SLC)    // 256 workgroups: (channel, batch-half, slice) -> 1 per CU
#define K2n  (Hn/2)        // 128 k-pairs
#define BUFS 4             // exchange buffers; coprime with tag period 3 -> exact freshness
#define EXU  (BUFS*Cn*K2n*Bn) // 8-byte units per layer exchange array
#define GP2  18            // gate-buffer pitch: quad stride 72B = 8 banks -> 2-way (free)

typedef __attribute__((ext_vector_type(8))) __bf16 bf16x8;
typedef __attribute__((ext_vector_type(8))) short  short8;
typedef __attribute__((ext_vector_type(4))) float  f32x4;
typedef __attribute__((ext_vector_type(4))) unsigned uintx4;
typedef unsigned long long u64;

__device__ __forceinline__ unsigned bfr(float f) {            // fp32 -> bf16 bits, RNE
    unsigned u = __float_as_uint(f);
    return (u + 0x7fffu + ((u >> 16) & 1u)) >> 16;
}
__device__ __forceinline__ float sigmf(float v)  { return 1.0f / (1.0f + __expf(-v)); }
__device__ __forceinline__ float tanh_f(float v) { return 1.0f - 2.0f / (__expf(2.0f * v) + 1.0f); }

__device__ __forceinline__ f32x4 mf(short8 a, short8 b, f32x4 c) {
    return __builtin_amdgcn_mfma_f32_16x16x32_bf16(
        __builtin_bit_cast(bf16x8, a), __builtin_bit_cast(bf16x8, b), c, 0, 0, 0);
}

// split 8 consecutive fp32 into bf16 hi + bf16 lo fragments
__device__ __forceinline__ void splitw(const float* __restrict__ p, short8& hi, short8& lo) {
    short8 h, l;
#pragma unroll
    for (int j = 0; j < 8; ++j) {
        const float v = p[j];
        const unsigned hb = bfr(v);
        h[j] = (short)hb;
        l[j] = (short)bfr(v - __uint_as_float(hb << 16));
    }
    hi = h; lo = l;
}

// agent-scope (Infinity-Cache) single-copy-atomic 8-byte ops.
// Tag and data travel in ONE atomic word -> no ordering/fence/scope assumptions.
__device__ __forceinline__ void ast64(u64* p, u64 v) {
    __hip_atomic_store(p, v, __ATOMIC_RELAXED, __HIP_MEMORY_SCOPE_AGENT);
}
__device__ __forceinline__ u64 ald64(const u64* p) {
    return __hip_atomic_load(p, __ATOMIC_RELAXED, __HIP_MEMORY_SCOPE_AGENT);
}

__global__ void __launch_bounds__(NTHR, 1)
lstm_mfma(const float* __restrict__ x,
          const float* __restrict__ Wih1, const float* __restrict__ Whh1,
          const float* __restrict__ bih1, const float* __restrict__ bhh1,
          const float* __restrict__ Wih2, const float* __restrict__ Whh2,
          const float* __restrict__ bih2, const float* __restrict__ bhh2,
          const float* __restrict__ Wlin, const float* __restrict__ blin,
          float* __restrict__ out, void* __restrict__ wsv, int use_part) {
    __shared__ float g1buf[2 * 64 * GP2];   // [kg][64 gate rows][16 b] layer-1 K-partials
    __shared__ float g2buf[2 * 64 * GP2];   // layer-2 K-partials

    // exchange arrays: [4 buf][C][K2=128][B=32] of (hi-pair dword, lo-pair dword)
    // lo-pair LSBs (u64 bits 32,48) carry a 2-bit step tag = (t mod 3)+1; 0 = unwritten.
    // BUFS=4 with tag period 3 (coprime): a matching tag implies data from EXACTLY
    // the expected step (stale candidates are 12 steps old, excluded by the
    // validation induction: observing tag t-1 proves all peers are past step t-1).
    u64* EX1 = (u64*)wsv;
    u64* EX2 = EX1 + EXU;
    float* part = (float*)(EX2 + EXU);      // [T][C][SLC][B] out partials

    const int tid  = threadIdx.x;
    const int wg   = blockIdx.x;
    const int c    = wg & 7;               // channel
    const int s    = (wg >> 3) & 15;       // slice: h-indices s*16 .. s*16+15
    const int bh   = (wg >> 7) & 1;        // batch-half: independent pipeline
    const int lane = tid & 63;
    const int wid  = tid >> 6;             // 4 waves
    const int kg   = wid & 1;              // K-group: k in [kg*128, kg*128+128)
    const int mh   = wid >> 1;             // M-half: rows mh*32 .. mh*32+31
    const int n    = lane & 15;
    const int quad = lane >> 4;
    const int bn   = bh * 16 + n;          // global batch of this lane's B-column

    // ---- permanent A-fragments: 3 weight matrices, 2 M-tiles, bf16 hi+lo, in VGPRs ----
    short8 w1h[2][4], w1l[2][4], w2h[2][4], w2l[2][4], w3h[2][4], w3l[2][4];
#pragma unroll
    for (int mt = 0; mt < 2; ++mt) {
        const int r = mh * 32 + mt * 16 + n;                  // wg row (0..63)
        const size_t g = (size_t)((r >> 4) * Hn + s * 16 + (r & 15));
        const size_t base = (size_t)c * Gn * Hn + g * Hn + kg * 128 + quad * 8;
#pragma unroll
        for (int kk = 0; kk < 4; ++kk) {
            splitw(Whh1 + base + kk * 32, w1h[mt][kk], w1l[mt][kk]);
            splitw(Wih2 + base + kk * 32, w2h[mt][kk], w2l[mt][kk]);
            splitw(Whh2 + base + kk * 32, w3h[mt][kk], w3l[mt][kk]);
        }
    }

    // epilogue constants for the 8 accumulator rows (row = mh*32 + mt*16 + quad*4 + reg)
    float wi1_r[2][4], bs1_r[2][4], bs2_r[2][4];
#pragma unroll
    for (int mt = 0; mt < 2; ++mt)
#pragma unroll
        for (int reg = 0; reg < 4; ++reg) {
            const int r = mh * 32 + mt * 16 + quad * 4 + reg;
            const int g = (r >> 4) * Hn + s * 16 + (r & 15);
            wi1_r[mt][reg] = Wih1[c * Gn + g];
            bs1_r[mt][reg] = bih1[c * Gn + g] + bhh1[c * Gn + g];
            bs2_r[mt][reg] = bih2[c * Gn + g] + bhh2[c * Gn + g];
        }

    // cell-update mapping: thread -> (jj = tid&15 h-idx within slice, bb = tid>>4 batch)
    const int jj = tid & 15;
    const int bb = tid >> 4;               // 0..15
    const int gb = bh * 16 + bb;           // global batch
    const float wl = Wlin[c * Hn + s * 16 + jj];
    const float bl = blin[c];

    float c1 = 0.0f, c2 = 0.0f;

    for (int t = 0; t <= Tn; ++t) {
        const bool doA = (t < Tn);      // layer-1 step t
        const bool doB = (t >= 1);      // layer-2 step t-1 (pipelined one behind)
        const int wb = t & 3;           // write buffer
        const int rb = (t + 3) & 3;     // read buffer (t-1 mod 4)
        const unsigned ctag = (unsigned)(t % 3) + 1u;
        const unsigned ptag = (unsigned)((t + 2) % 3) + 1u;

        const float xv = doA ? x[(bn * Tn + t) * Cn + c] : 0.0f;

        const u64* E1 = EX1 + (size_t)(rb * Cn + c) * K2n * Bn;
        const u64* E2 = EX2 + (size_t)(rb * Cn + c) * K2n * Bn;
        const unsigned em = (ptag & 1u) | ((ptag & 2u) << 15);   // expected bits at lo0,lo16
        const bool chk1 = (t >= 1);     // E1 first written at producer step 0
        const bool chk2 = (t >= 2);     // E2 first written at producer step 1

        // ---- phase 1: poll E2 (h2[t-2]) — the lead wait; h1's wait hides below ----
        f32x4 a2a[2] = {{0,0,0,0},{0,0,0,0}}, a2x[2] = {{0,0,0,0},{0,0,0,0}};
        {
            short8 f2h[4], f2l[4];
            for (;;) {
                unsigned bad = 0;
#pragma unroll
                for (int kk = 0; kk < 4; ++kk) {
                    uintx4 ah, al;
#pragma unroll
                    for (int j2 = 0; j2 < 4; ++j2) {
                        const int k2 = kg * 64 + kk * 16 + quad * 4 + j2;
                        const u64 v2 = ald64(E2 + k2 * Bn + bn);
                        ah[j2] = (unsigned)v2;
                        al[j2] = (unsigned)(v2 >> 32);
                        bad |= (al[j2] ^ em) & 0x00010001u;
                    }
                    f2h[kk] = __builtin_bit_cast(short8, ah);
                    f2l[kk] = __builtin_bit_cast(short8, al);
                }
                if (!chk2 || __all((int)(bad == 0))) break;
                __builtin_amdgcn_s_sleep(1);
            }
            // ---- phase 2: Whh2 MFMAs (f2 dies here -> no f1+f2 pressure spike) ----
#pragma unroll
            for (int kk = 0; kk < 4; ++kk)
#pragma unroll
                for (int mt = 0; mt < 2; ++mt) {
                    a2a[mt] = mf(w3h[mt][kk], f2h[kk], a2a[mt]);
                    a2x[mt] = mf(w3l[mt][kk], f2h[kk], mf(w3h[mt][kk], f2l[kk], a2x[mt]));
                }
        }

        // ---- phase 3: poll E1 (h1[t-1]) — visibility hidden under phases 1-2 ----
        f32x4 a1a[2] = {{0,0,0,0},{0,0,0,0}}, a1x[2] = {{0,0,0,0},{0,0,0,0}};
        {
            short8 f1h[4], f1l[4];
            for (;;) {
                unsigned bad = 0;
#pragma unroll
                for (int kk = 0; kk < 4; ++kk) {
                    uintx4 ah, al;
#pragma unroll
                    for (int j2 = 0; j2 < 4; ++j2) {
                        const int k2 = kg * 64 + kk * 16 + quad * 4 + j2;
                        const u64 v1 = ald64(E1 + k2 * Bn + bn);
                        ah[j2] = (unsigned)v1;
                        al[j2] = (unsigned)(v1 >> 32);
                        bad |= (al[j2] ^ em) & 0x00010001u;
                    }
                    f1h[kk] = __builtin_bit_cast(short8, ah);
                    f1l[kk] = __builtin_bit_cast(short8, al);
                }
                if (!chk1 || __all((int)(bad == 0))) break;
                __builtin_amdgcn_s_sleep(1);
            }
            // ---- phase 4: Whh1 + Wih2 MFMAs (both consume f1) ----
#pragma unroll
            for (int kk = 0; kk < 4; ++kk)
#pragma unroll
                for (int mt = 0; mt < 2; ++mt) {
                    a1a[mt] = mf(w1h[mt][kk], f1h[kk], a1a[mt]);
                    a1x[mt] = mf(w1l[mt][kk], f1h[kk], mf(w1h[mt][kk], f1l[kk], a1x[mt]));
                    a2a[mt] = mf(w2h[mt][kk], f1h[kk], a2a[mt]);
                    a2x[mt] = mf(w2l[mt][kk], f1h[kk], mf(w2h[mt][kk], f1l[kk], a2x[mt]));
                }
        }

        // ---- write K-partial gates to LDS (C/D layout: col=lane&15, row=quad*4+reg) ----
#pragma unroll
        for (int mt = 0; mt < 2; ++mt)
#pragma unroll
            for (int reg = 0; reg < 4; ++reg) {
                const int r = mh * 32 + mt * 16 + quad * 4 + reg;      // 0..63
                const int off = (kg * 64 + r) * GP2 + n;
                float e1 = a1a[mt][reg] + a1x[mt][reg];
                float e2 = a2a[mt][reg] + a2x[mt][reg];
                if (kg == 0) {                       // bias/x terms added once
                    e1 += xv * wi1_r[mt][reg] + bs1_r[mt][reg];
                    e2 += bs2_r[mt][reg];
                }
                g1buf[off] = e1;
                g2buf[off] = e2;
            }
        __syncthreads();

        const unsigned cm = (ctag & 1u) | ((ctag & 2u) << 15);   // publish tag bits

        // ---- layer-2 cell FIRST: h2[t-1] is polled first next step -> publish ASAP ----
        float h2v = 0.0f;
        if (doB) {
            const float iv = sigmf (g2buf[jj * GP2 + bb]        + g2buf[(64 + jj) * GP2 + bb]);
            const float fv = sigmf (g2buf[(16 + jj) * GP2 + bb] + g2buf[(80 + jj) * GP2 + bb]);
            const float gv = tanh_f(g2buf[(32 + jj) * GP2 + bb] + g2buf[(96 + jj) * GP2 + bb]);
            const float ov = sigmf (g2buf[(48 + jj) * GP2 + bb] + g2buf[(112 + jj) * GP2 + bb]);
            c2 = fv * c2 + iv * gv;
            h2v = ov * tanh_f(c2);
            if (t < Tn) {                 // last iteration's h2 has no reader
                const unsigned hb = bfr(h2v);
                const unsigned lb = bfr(h2v - __uint_as_float(hb << 16));
                const unsigned packed = (hb << 16) | lb;
                const unsigned nbp = (unsigned)__shfl_xor((int)packed, 1, 64);
                if ((jj & 1) == 0) {
                    const unsigned hip = (packed >> 16) | (nbp & 0xffff0000u);
                    unsigned lop = (packed & 0xffffu) | (nbp << 16);
                    lop = (lop & 0xFFFEFFFEu) | cm;
                    const int k2 = s * 8 + (jj >> 1);
                    ast64(EX2 + (size_t)(wb * Cn + c) * K2n * Bn + k2 * Bn + gb,
                          (u64)hip | ((u64)lop << 32));
                }
            } else {
                (void)__shfl_xor(0, 1, 64);          // keep shuffle pattern uniform
            }
        }

        // ---- layer-1 cell update, publish h1[t] ----
        if (doA) {
            const float iv = sigmf (g1buf[jj * GP2 + bb]        + g1buf[(64 + jj) * GP2 + bb]);
            const float fv = sigmf (g1buf[(16 + jj) * GP2 + bb] + g1buf[(80 + jj) * GP2 + bb]);
            const float gv = tanh_f(g1buf[(32 + jj) * GP2 + bb] + g1buf[(96 + jj) * GP2 + bb]);
            const float ov = sigmf (g1buf[(48 + jj) * GP2 + bb] + g1buf[(112 + jj) * GP2 + bb]);
            c1 = fv * c1 + iv * gv;
            const float h1v = ov * tanh_f(c1);
            const unsigned hb = bfr(h1v);
            const unsigned lb = bfr(h1v - __uint_as_float(hb << 16));
            const unsigned packed = (hb << 16) | lb;
            const unsigned nbp = (unsigned)__shfl_xor((int)packed, 1, 64);
            if ((jj & 1) == 0) {
                const unsigned hip = (packed >> 16) | (nbp & 0xffff0000u);
                unsigned lop = (packed & 0xffffu) | (nbp << 16);
                lop = (lop & 0xFFFEFFFEu) | cm;                  // steal lo LSBs for tag
                const int k2 = s * 8 + (jj >> 1);
                ast64(EX1 + (size_t)(wb * Cn + c) * K2n * Bn + k2 * Bn + gb,
                      (u64)hip | ((u64)lop << 32));
            }
        }

        // ---- out partial (off the critical publish path) ----
        if (doB) {
            float pv = h2v * wl;                      // partial of out over this slice's 16 h
            pv += __shfl_xor(pv, 1, 64);
            pv += __shfl_xor(pv, 2, 64);
            pv += __shfl_xor(pv, 4, 64);
            pv += __shfl_xor(pv, 8, 64);
            if (jj == 0) {
                if (use_part) {
                    part[(((t - 1) * Cn + c) * SLC + s) * Bn + gb] = pv;
                } else {
                    atomicAdd(&out[(gb * Tn + (t - 1)) * Cn + c], pv + (s == 0 ? bl : 0.0f));
                }
            }
        }

        __syncthreads();   // WAR on gate LDS buffers (no global barrier needed)
    }
}

__global__ void reduce_out(const float* __restrict__ part, const float* __restrict__ blin,
                           float* __restrict__ out) {
    const int t = blockIdx.x;           // 512
    const int c = threadIdx.x >> 5;     // 8
    const int b = threadIdx.x & 31;     // 32
    float v = blin[c];
#pragma unroll
    for (int s = 0; s < SLC; ++s) v += part[((t * Cn + c) * SLC + s) * Bn + b];
    out[(b * Tn + t) * Cn + c] = v;
}

extern "C" void kernel_launch(void* const* d_in, const int* in_sizes, int n_in,
                              void* d_out, int out_size, void* d_ws, size_t ws_size,
                              hipStream_t stream) {
    const float* x    = (const float*)d_in[0];
    const float* Wih1 = (const float*)d_in[1];
    const float* Whh1 = (const float*)d_in[2];
    const float* bih1 = (const float*)d_in[3];
    const float* bhh1 = (const float*)d_in[4];
    const float* Wih2 = (const float*)d_in[5];
    const float* Whh2 = (const float*)d_in[6];
    const float* bih2 = (const float*)d_in[7];
    const float* bhh2 = (const float*)d_in[8];
    const float* Wlin = (const float*)d_in[9];
    const float* blin = (const float*)d_in[10];
    float* out = (float*)d_out;

    const size_t h_bytes    = (size_t)2 * EXU * sizeof(u64);                // 2 MiB
    const size_t part_bytes = (size_t)Tn * Cn * SLC * Bn * sizeof(float);   // 8 MiB
    const int use_part = (ws_size >= h_bytes + part_bytes) ? 1 : 0;

    hipMemsetAsync(d_ws, 0, h_bytes, stream);   // zero h-exchange (tag 0 = unwritten)
    if (!use_part)
        hipMemsetAsync(d_out, 0, (size_t)out_size * sizeof(float), stream);

    lstm_mfma<<<NBLK, NTHR, 0, stream>>>(
        x, Wih1, Whh1, bih1, bhh1, Wih2, Whh2, bih2, bhh2, Wlin, blin, out, d_ws, use_part);

    if (use_part) {
        const float* part = (const float*)((const char*)d_ws + h_bytes);
        reduce_out<<<Tn, Cn * Bn, 0, stream>>>(part, blin, out);
    }
}